// Round 9
// baseline (675.858 us; speedup 1.0000x reference)
//
#include <hip/hip_runtime.h>
#include <cstdint>
#include <cstddef>

// ---------- types / helpers ----------
typedef float  f32x4  __attribute__((ext_vector_type(4)));
typedef float  f32x2  __attribute__((ext_vector_type(2)));

__device__ __forceinline__ unsigned int f2fp8x4(float a, float b, float c, float d) {
  int v = __builtin_amdgcn_cvt_pk_fp8_f32(a, b, 0, false);
  v = __builtin_amdgcn_cvt_pk_fp8_f32(c, d, v, true);
  return (unsigned int)v;
}
__device__ __forceinline__ unsigned char f2fp8(float f) {
  return (unsigned char)(__builtin_amdgcn_cvt_pk_fp8_f32(f, f, 0, false) & 0xff);
}
__device__ __forceinline__ void fp8x8_to_f32(uint2 d, float* f) {
  f32x2 a = __builtin_amdgcn_cvt_pk_f32_fp8((int)d.x, false);
  f32x2 b = __builtin_amdgcn_cvt_pk_f32_fp8((int)d.x, true);
  f32x2 c = __builtin_amdgcn_cvt_pk_f32_fp8((int)d.y, false);
  f32x2 e = __builtin_amdgcn_cvt_pk_f32_fp8((int)d.y, true);
  f[0] = a.x; f[1] = a.y; f[2] = b.x; f[3] = b.y;
  f[4] = c.x; f[5] = c.y; f[6] = e.x; f[7] = e.y;
}
__device__ __forceinline__ void fp8x4_to_f32(unsigned int d, float* f) {
  f32x2 a = __builtin_amdgcn_cvt_pk_f32_fp8((int)d, false);
  f32x2 b = __builtin_amdgcn_cvt_pk_f32_fp8((int)d, true);
  f[0] = a.x; f[1] = a.y; f[2] = b.x; f[3] = b.y;
}

// async global->LDS, 16B per lane. LDS dest must be lane-contiguous in wave order.
__device__ __forceinline__ void async_copy16(const void* g, void* l) {
  __builtin_amdgcn_global_load_lds(
      (const __attribute__((address_space(1))) unsigned int*)g,
      (__attribute__((address_space(3))) unsigned int*)l, 16, 0, 0);
}

#define NN 50000
#define MPAD 50048       // 391 * 128
#define SCAN_BLOCKS 196  // ceil(50000/256)
#define MEGA_BLOCKS 512  // 2 blocks/CU -> guaranteed co-resident (software grid barrier)

// software grid barrier: per-phase counter in `bar` (zeroed by memset before launch).
__device__ __forceinline__ void gridbar(int* bar, int idx, int nblk) {
  __threadfence();        // make this thread's prior writes device-visible (L2 wb)
  __syncthreads();
  if (threadIdx.x == 0) {
    __hip_atomic_fetch_add(&bar[idx], 1, __ATOMIC_RELEASE, __HIP_MEMORY_SCOPE_AGENT);
    while (__hip_atomic_load(&bar[idx], __ATOMIC_ACQUIRE, __HIP_MEMORY_SCOPE_AGENT) < nblk) {}
  }
  __syncthreads();
}

// ---------- mega: prep (X/W -> fp8) + degree count + scan + edge scatter ----------
__global__ __launch_bounds__(256) void gcn_mega_k(
    const float* __restrict__ X, unsigned char* __restrict__ x8,
    const float* __restrict__ W1, const float* __restrict__ W2,
    const float* __restrict__ W3,
    unsigned char* __restrict__ W1T8, unsigned char* __restrict__ W2T8,
    unsigned char* __restrict__ W3T8,
    const int* __restrict__ src, const int* __restrict__ dst, int E,
    int* __restrict__ cnt, int* __restrict__ rs, int* __restrict__ cur,
    float* __restrict__ dinv, int2* __restrict__ e2,
    int* __restrict__ bsum, int* __restrict__ bscan, int* __restrict__ bar) {
  const int nb = gridDim.x;
  const int b = blockIdx.x, t = threadIdx.x;
  const int gtid = b * 256 + t, gstride = nb * 256;
  __shared__ int sb[256];

  // ---- phase 0: streaming format conversion (no ordering deps) ----
  // X [NN x 512] f32 -> x8 [MPAD x 512] fp8 (pad rows zero): 16 elems/unit
  for (int u = gtid; u < (MPAD * 512 / 16); u += gstride) {
    int idx16 = u * 16;
    int row = idx16 >> 9;
    uint4 o;
    if (row < NN) {
      const float* s = &X[idx16];
      float4 v0 = *(const float4*)s;
      float4 v1 = *(const float4*)(s + 4);
      float4 v2 = *(const float4*)(s + 8);
      float4 v3 = *(const float4*)(s + 12);
      o.x = f2fp8x4(v0.x, v0.y, v0.z, v0.w);
      o.y = f2fp8x4(v1.x, v1.y, v1.z, v1.w);
      o.z = f2fp8x4(v2.x, v2.y, v2.z, v2.w);
      o.w = f2fp8x4(v3.x, v3.y, v3.z, v3.w);
    } else {
      o = uint4{0, 0, 0, 0};
    }
    *(uint4*)&x8[idx16] = o;
  }
  // W1 [512x256] -> W1T8 [256x512] fp8
  for (int u = gtid; u < (256 * 512 / 16); u += gstride) {
    int idx16 = u * 16;
    int n = idx16 >> 9;
    float f[16];
#pragma unroll
    for (int j = 0; j < 16; j++) f[j] = W1[(size_t)((idx16 & 511) + j) * 256 + n];
    uint4 o;
    o.x = f2fp8x4(f[0], f[1], f[2], f[3]);
    o.y = f2fp8x4(f[4], f[5], f[6], f[7]);
    o.z = f2fp8x4(f[8], f[9], f[10], f[11]);
    o.w = f2fp8x4(f[12], f[13], f[14], f[15]);
    *(uint4*)&W1T8[idx16] = o;
  }
  // W2 [256x256] -> W2T8 [256x256] fp8
  for (int u = gtid; u < (256 * 256 / 16); u += gstride) {
    int idx16 = u * 16;
    int n = idx16 >> 8;
    float f[16];
#pragma unroll
    for (int j = 0; j < 16; j++) f[j] = W2[(size_t)((idx16 & 255) + j) * 256 + n];
    uint4 o;
    o.x = f2fp8x4(f[0], f[1], f[2], f[3]);
    o.y = f2fp8x4(f[4], f[5], f[6], f[7]);
    o.z = f2fp8x4(f[8], f[9], f[10], f[11]);
    o.w = f2fp8x4(f[12], f[13], f[14], f[15]);
    *(uint4*)&W2T8[idx16] = o;
  }
  // W3 [256x64] -> W3T8 [64x256] fp8
  for (int u = gtid; u < (64 * 256 / 16); u += gstride) {
    int idx16 = u * 16;
    int n = idx16 >> 8;
    float f[16];
#pragma unroll
    for (int j = 0; j < 16; j++) f[j] = W3[(size_t)((idx16 & 255) + j) * 64 + n];
    uint4 o;
    o.x = f2fp8x4(f[0], f[1], f[2], f[3]);
    o.y = f2fp8x4(f[4], f[5], f[6], f[7]);
    o.z = f2fp8x4(f[8], f[9], f[10], f[11]);
    o.w = f2fp8x4(f[12], f[13], f[14], f[15]);
    *(uint4*)&W3T8[idx16] = o;
  }

  // ---- phase a: degree count (cnt zeroed by host-side memset) ----
  for (int e = gtid; e < E; e += gstride) atomicAdd(&cnt[dst[e]], 1);
  gridbar(bar, 0, nb);

  // ---- phase b: per-scan-block partial sums ----
  if (b < SCAN_BLOCKS) {
    int i = b * 256 + t;
    int v = (i < NN) ? cnt[i] : 0;
    for (int off = 32; off > 0; off >>= 1) v += __shfl_down(v, off);
    __shared__ int sw[4];
    if ((t & 63) == 0) sw[t >> 6] = v;
    __syncthreads();
    if (t == 0) bsum[b] = sw[0] + sw[1] + sw[2] + sw[3];
  }
  gridbar(bar, 1, nb);

  // ---- phase c: block 0 scans the block sums -> bscan (fresh array: no stale L2 copies) ----
  if (b == 0) {
    int v = (t < SCAN_BLOCKS) ? bsum[t] : 0;
    sb[t] = v;
    __syncthreads();
    for (int off = 1; off < 256; off <<= 1) {
      int x = (t >= off) ? sb[t - off] : 0;
      __syncthreads();
      sb[t] += x;
      __syncthreads();
    }
    if (t < SCAN_BLOCKS) bscan[t] = sb[t] - v;  // exclusive
  }
  gridbar(bar, 2, nb);

  // ---- phase d: intra-block exclusive scan, write rs/cur/dinv ----
  if (b < SCAN_BLOCKS) {
    int i = b * 256 + t;
    int v = (i < NN) ? cnt[i] : 0;
    sb[t] = v;
    __syncthreads();
    for (int off = 1; off < 256; off <<= 1) {
      int x = (t >= off) ? sb[t - off] : 0;
      __syncthreads();
      sb[t] += x;
      __syncthreads();
    }
    if (i < NN) {
      int off = bscan[b] + sb[t] - v;
      rs[i] = off; cur[i] = off;
      dinv[i] = rsqrtf(1.0f + (float)v);
    }
    if (i == 0) rs[NN] = E;
  }
  gridbar(bar, 3, nb);

  // ---- phase e: scatter edges sorted by dst, pack (src, norm) ----
  for (int e = gtid; e < E; e += gstride) {
    int d = dst[e];
    int s = src[e];
    int p = atomicAdd(&cur[d], 1);
    int2 v; v.x = s; v.y = __float_as_int(dinv[s] * dinv[d]);
    e2[p] = v;
  }
}

// ---------- fp8 x fp8 MFMA GEMM, fp8 out: C8 = fp8(A8 @ Bt8^T), 128 x BN tile ----------
template<int BN, int WTN>
__global__ __launch_bounds__(256) void gcn_gemm_f8_k(
    const unsigned char* __restrict__ A8,   // [MPAD x K] fp8
    const unsigned char* __restrict__ Bt8,  // [N x K]    fp8
    unsigned char* __restrict__ C8,         // [MPAD x N] fp8
    int K, int N) {
  __shared__ __align__(16) unsigned char lds_a[128 * 32];
  __shared__ __align__(16) unsigned char lds_b[BN * 32];
  const int t = threadIdx.x;
  const int wave = t >> 6, lane = t & 63;
  const int wr = wave >> 1, wc = wave & 1;
  const int quad = lane >> 4, lrow = lane & 15;
  const int m0 = blockIdx.x * 128;
  const int n0 = blockIdx.y * BN;

  f32x4 acc[4][WTN] = {};

  for (int k0 = 0; k0 < K; k0 += 32) {
    __syncthreads();
    {
      int r = t >> 1, c = (t & 1) * 16;
      async_copy16(&A8[(size_t)(m0 + r) * K + k0 + c], &lds_a[t * 16]);
    }
    for (int q = t; q < BN * 2; q += 256) {
      int r = q >> 1, c = (q & 1) * 16;
      async_copy16(&Bt8[(size_t)(n0 + r) * K + k0 + c], &lds_b[q * 16]);
    }
    __syncthreads();
    long af[4], bfr[WTN];
#pragma unroll
    for (int mt = 0; mt < 4; mt++)
      af[mt] = *(const long*)&lds_a[(wr * 64 + mt * 16 + lrow) * 32 + quad * 8];
#pragma unroll
    for (int nt = 0; nt < WTN; nt++)
      bfr[nt] = *(const long*)&lds_b[(wc * (BN / 2) + nt * 16 + lrow) * 32 + quad * 8];
#pragma unroll
    for (int mt = 0; mt < 4; mt++)
#pragma unroll
      for (int nt = 0; nt < WTN; nt++)
        acc[mt][nt] = __builtin_amdgcn_mfma_f32_16x16x32_fp8_fp8(af[mt], bfr[nt], acc[mt][nt], 0, 0, 0);
  }

#pragma unroll
  for (int mt = 0; mt < 4; mt++)
#pragma unroll
    for (int nt = 0; nt < WTN; nt++)
#pragma unroll
      for (int r = 0; r < 4; r++) {
        int row = m0 + wr * 64 + mt * 16 + quad * 4 + r;
        int col = n0 + wc * (BN / 2) + nt * 16 + lrow;
        C8[(size_t)row * N + col] = f2fp8(acc[mt][nt][r]);
      }
}

// ---------- aggregation over fp8 rows, fused bias+self+ReLU, fp8 out ----------
// 2 edges per wave (32 lanes x 8B fp8 per row), unroll x4 -> 8 edges in flight.
template<int D>  // D = 256
__global__ __launch_bounds__(256) void gcn_agg_relu_k(
    const unsigned char* __restrict__ h8, const int* __restrict__ rs,
    const int2* __restrict__ e2, const float* __restrict__ dinv,
    const float* __restrict__ bias, unsigned char* __restrict__ out8, int nNodes) {
  int wave = threadIdx.x >> 6, lane = threadIdx.x & 63;
  int i = blockIdx.x * 4 + wave;
  if (i >= nNodes) return;
  int half = lane >> 5, sub = lane & 31;
  int f0 = sub * 8;
  float di = dinv[i];
  uint2 dsel = *(const uint2*)&h8[(size_t)i * D + f0];
  float sv[8];
  fp8x8_to_f32(dsel, sv);
  float wself = (half == 0) ? di * di : 0.0f;
  float acc[8];
#pragma unroll
  for (int j = 0; j < 8; j++) acc[j] = sv[j] * wself;

  int e0 = rs[i], e1 = rs[i + 1];
  int nIter = (e1 - e0 + 7) >> 3;
  int e = e0 + half;
  for (int k = 0; k < nIter; k++) {
    int idx[4]; float w[4];
#pragma unroll
    for (int u = 0; u < 4; u++) {
      int ee = e + 2 * u;
      bool v = ee < e1;
      int2 pr = e2[v ? ee : e0];
      idx[u] = v ? pr.x : i;
      w[u] = v ? __int_as_float(pr.y) : 0.0f;
    }
    uint2 d0 = *(const uint2*)&h8[(size_t)idx[0] * D + f0];
    uint2 d1 = *(const uint2*)&h8[(size_t)idx[1] * D + f0];
    uint2 d2 = *(const uint2*)&h8[(size_t)idx[2] * D + f0];
    uint2 d3 = *(const uint2*)&h8[(size_t)idx[3] * D + f0];
    float r0[8], r1[8], r2[8], r3[8];
    fp8x8_to_f32(d0, r0); fp8x8_to_f32(d1, r1);
    fp8x8_to_f32(d2, r2); fp8x8_to_f32(d3, r3);
#pragma unroll
    for (int j = 0; j < 8; j++)
      acc[j] += r0[j] * w[0] + r1[j] * w[1] + r2[j] * w[2] + r3[j] * w[3];
    e += 8;
  }
#pragma unroll
  for (int j = 0; j < 8; j++) acc[j] += __shfl_xor(acc[j], 32);
  if (half == 0) {
    float r[8];
#pragma unroll
    for (int j = 0; j < 8; j++) {
      float z = acc[j] + bias[f0 + j];
      r[j] = z > 0.0f ? z : 0.0f;
    }
    uint2 o;
    o.x = f2fp8x4(r[0], r[1], r[2], r[3]);
    o.y = f2fp8x4(r[4], r[5], r[6], r[7]);
    *(uint2*)&out8[(size_t)i * D + f0] = o;
  }
}

// final layer: D=64 fp8 rows; 4 edges per wave (16 lanes x 4B), softmax+log_softmax
__global__ __launch_bounds__(256) void gcn_agg_final_k(
    const unsigned char* __restrict__ h8, const int* __restrict__ rs,
    const int2* __restrict__ e2, const float* __restrict__ dinv,
    const float* __restrict__ bias, float* __restrict__ out, int nNodes) {
  int wave = threadIdx.x >> 6, lane = threadIdx.x & 63;
  int i = blockIdx.x * 4 + wave;
  if (i >= nNodes) return;
  int qtr = lane >> 4, sub = lane & 15;
  int f0 = sub * 4;
  float di = dinv[i];
  unsigned int dself = *(const unsigned int*)&h8[(size_t)i * 64 + f0];
  float sv[4];
  fp8x4_to_f32(dself, sv);
  float wself = (qtr == 0) ? di * di : 0.0f;
  float acc[4];
#pragma unroll
  for (int j = 0; j < 4; j++) acc[j] = sv[j] * wself;

  int e0 = rs[i], e1 = rs[i + 1];
  int nIter = (e1 - e0 + 7) >> 3;
  int e = e0 + qtr;
  for (int k = 0; k < nIter; k++) {
    int idx[2]; float w[2];
#pragma unroll
    for (int u = 0; u < 2; u++) {
      int ee = e + 4 * u;
      bool v = ee < e1;
      int2 pr = e2[v ? ee : e0];
      idx[u] = v ? pr.x : i;
      w[u] = v ? __int_as_float(pr.y) : 0.0f;
    }
    unsigned int d0 = *(const unsigned int*)&h8[(size_t)idx[0] * 64 + f0];
    unsigned int d1 = *(const unsigned int*)&h8[(size_t)idx[1] * 64 + f0];
    float r0[4], r1[4];
    fp8x4_to_f32(d0, r0); fp8x4_to_f32(d1, r1);
#pragma unroll
    for (int j = 0; j < 4; j++)
      acc[j] += r0[j] * w[0] + r1[j] * w[1];
    e += 8;
  }
#pragma unroll
  for (int j = 0; j < 4; j++) {
    acc[j] += __shfl_xor(acc[j], 16);
    acc[j] += __shfl_xor(acc[j], 32);
    acc[j] += bias[f0 + j];
  }
  // softmax over 64 features (16 lanes x 4 regs; all lanes hold full sums)
  float m = fmaxf(fmaxf(acc[0], acc[1]), fmaxf(acc[2], acc[3]));
#pragma unroll
  for (int off = 8; off > 0; off >>= 1) m = fmaxf(m, __shfl_xor(m, off));
  float ex[4], s = 0.0f;
#pragma unroll
  for (int j = 0; j < 4; j++) { ex[j] = __expf(acc[j] - m); s += ex[j]; }
#pragma unroll
  for (int off = 8; off > 0; off >>= 1) s += __shfl_xor(s, off);
  float rcs = 1.0f / s;
  float p[4], s2 = 0.0f;
#pragma unroll
  for (int j = 0; j < 4; j++) { p[j] = ex[j] * rcs; s2 += __expf(p[j]); }
#pragma unroll
  for (int off = 8; off > 0; off >>= 1) s2 += __shfl_xor(s2, off);
  float ls = __logf(s2);
  if (qtr == 0) {
    float4 o; o.x = p[0] - ls; o.y = p[1] - ls; o.z = p[2] - ls; o.w = p[3] - ls;
    *(float4*)&out[(size_t)i * 64 + f0] = o;
  }
}

// ---------- launch ----------
extern "C" void kernel_launch(void* const* d_in, const int* in_sizes, int n_in,
                              void* d_out, int out_size, void* d_ws, size_t ws_size,
                              hipStream_t stream) {
  const float* x    = (const float*)d_in[0];
  const int*   eidx = (const int*)d_in[1];
  const float* W1   = (const float*)d_in[2];
  const float* b1   = (const float*)d_in[3];
  const float* W2   = (const float*)d_in[4];
  const float* b2   = (const float*)d_in[5];
  const float* W3   = (const float*)d_in[6];
  const float* b3   = (const float*)d_in[7];
  float* out = (float*)d_out;

  const int E = in_sizes[1] / 2;            // 800000
  const int* src = eidx;
  const int* dst = eidx + E;

  char* p = (char*)d_ws;
  auto alloc = [&](size_t bytes) -> void* {
    void* r = (void*)p;
    p += (bytes + 255) & ~(size_t)255;
    return r;
  };
  unsigned char*  x8   = (unsigned char*)alloc((size_t)MPAD * 512);
  unsigned char*  g8   = (unsigned char*)alloc((size_t)MPAD * 256);  // gemm out fp8
  unsigned char*  a8   = (unsigned char*)alloc((size_t)MPAD * 256);  // agg out fp8
  unsigned char*  g83  = (unsigned char*)alloc((size_t)MPAD * 64);
  unsigned char*  W1T8 = (unsigned char*)alloc((size_t)256 * 512);
  unsigned char*  W2T8 = (unsigned char*)alloc((size_t)256 * 256);
  unsigned char*  W3T8 = (unsigned char*)alloc((size_t)64 * 256);
  int*   cz   = (int*)alloc((size_t)(NN + 8) * 4);  // cnt + barrier counters (one memset)
  int*   cnt  = cz;
  int*   bar  = cz + NN;
  int*   rs   = (int*)alloc((size_t)(NN + 1) * 4);
  int*   cur  = (int*)alloc((size_t)NN * 4);
  float* dinv = (float*)alloc((size_t)NN * 4);
  int2*  e2   = (int2*)alloc((size_t)E * 8);
  int*   bsum  = (int*)alloc((size_t)SCAN_BLOCKS * 4);
  int*   bscan = (int*)alloc((size_t)SCAN_BLOCKS * 4);

  hipMemsetAsync(cz, 0, (size_t)(NN + 8) * 4, stream);
  gcn_mega_k<<<MEGA_BLOCKS, 256, 0, stream>>>(
      x, x8, W1, W2, W3, W1T8, W2T8, W3T8,
      src, dst, E, cnt, rs, cur, dinv, e2, bsum, bscan, bar);

  const int MB = MPAD / 128;  // 391
  // layer 1 (fp8)
  gcn_gemm_f8_k<128, 4><<<dim3(MB, 2), 256, 0, stream>>>(x8, W1T8, g8, 512, 256);
  gcn_agg_relu_k<256><<<(NN + 3) / 4, 256, 0, stream>>>(g8, rs, e2, dinv, b1, a8, NN);
  // layer 2 (fp8)
  gcn_gemm_f8_k<128, 4><<<dim3(MB, 2), 256, 0, stream>>>(a8, W2T8, g8, 256, 256);
  gcn_agg_relu_k<256><<<(NN + 3) / 4, 256, 0, stream>>>(g8, rs, e2, dinv, b2, a8, NN);
  // layer 3 (fp8) + fused softmax/log_softmax
  gcn_gemm_f8_k<64, 2><<<dim3(MB, 1), 256, 0, stream>>>(a8, W3T8, g83, 256, 64);
  gcn_agg_final_k<<<(NN + 3) / 4, 256, 0, stream>>>(g83, rs, e2, dinv, b3, out, NN);

  (void)n_in; (void)out_size; (void)ws_size;
}

// Round 10
// 417.869 us; speedup vs baseline: 1.6174x; 1.6174x over previous
//
#include <hip/hip_runtime.h>
#include <cstdint>
#include <cstddef>

// ---------- types / helpers ----------
typedef float  f32x4  __attribute__((ext_vector_type(4)));
typedef float  f32x2  __attribute__((ext_vector_type(2)));

__device__ __forceinline__ unsigned int f2fp8x4(float a, float b, float c, float d) {
  int v = __builtin_amdgcn_cvt_pk_fp8_f32(a, b, 0, false);
  v = __builtin_amdgcn_cvt_pk_fp8_f32(c, d, v, true);
  return (unsigned int)v;
}
__device__ __forceinline__ unsigned char f2fp8(float f) {
  return (unsigned char)(__builtin_amdgcn_cvt_pk_fp8_f32(f, f, 0, false) & 0xff);
}
__device__ __forceinline__ void fp8x8_to_f32(uint2 d, float* f) {
  f32x2 a = __builtin_amdgcn_cvt_pk_f32_fp8((int)d.x, false);
  f32x2 b = __builtin_amdgcn_cvt_pk_f32_fp8((int)d.x, true);
  f32x2 c = __builtin_amdgcn_cvt_pk_f32_fp8((int)d.y, false);
  f32x2 e = __builtin_amdgcn_cvt_pk_f32_fp8((int)d.y, true);
  f[0] = a.x; f[1] = a.y; f[2] = b.x; f[3] = b.y;
  f[4] = c.x; f[5] = c.y; f[6] = e.x; f[7] = e.y;
}
__device__ __forceinline__ void fp8x4_to_f32(unsigned int d, float* f) {
  f32x2 a = __builtin_amdgcn_cvt_pk_f32_fp8((int)d, false);
  f32x2 b = __builtin_amdgcn_cvt_pk_f32_fp8((int)d, true);
  f[0] = a.x; f[1] = a.y; f[2] = b.x; f[3] = b.y;
}

// async global->LDS, 16B per lane. LDS dest must be lane-contiguous in wave order.
__device__ __forceinline__ void async_copy16(const void* g, void* l) {
  __builtin_amdgcn_global_load_lds(
      (const __attribute__((address_space(1))) unsigned int*)g,
      (__attribute__((address_space(3))) unsigned int*)l, 16, 0, 0);
}

#define NN 50000
#define MPAD 50048       // 391 * 128
#define SCAN_BLOCKS 196  // ceil(50000/256)

// prep block ranges: X (6256) + W1 (32) + W2 (16) + W3 (4)
#define XB_BLOCKS 6256   // MPAD*512/16/256
#define WB_BLOCKS 52

__global__ void gcn_zero_k(int* __restrict__ p, int n) {
  int i = blockIdx.x * 256 + threadIdx.x;
  if (i < n) p[i] = 0;
}

__global__ void gcn_count_k(const int* __restrict__ dst, int* __restrict__ cnt, int E) {
  int e = blockIdx.x * 256 + threadIdx.x;
  if (e < E) atomicAdd(&cnt[dst[e]], 1);
}

// ---------- prep (pure streaming, full occupancy): X,W1,W2,W3 -> fp8 (transposed W) ----------
__global__ __launch_bounds__(256) void gcn_prep_k(
    const float* __restrict__ X, unsigned char* __restrict__ x8,
    const float* __restrict__ W1, const float* __restrict__ W2,
    const float* __restrict__ W3,
    unsigned char* __restrict__ W1T8, unsigned char* __restrict__ W2T8,
    unsigned char* __restrict__ W3T8) {
  int b = blockIdx.x;
  if (b < XB_BLOCKS) {
    // X [NN x 512] f32 -> x8 [MPAD x 512] fp8, 16 elems/thread
    int idx16 = (b * 256 + threadIdx.x) * 16;
    int row = idx16 >> 9;
    uint4 o;
    if (row < NN) {
      const float* s = &X[idx16];
      float4 v0 = *(const float4*)s;
      float4 v1 = *(const float4*)(s + 4);
      float4 v2 = *(const float4*)(s + 8);
      float4 v3 = *(const float4*)(s + 12);
      o.x = f2fp8x4(v0.x, v0.y, v0.z, v0.w);
      o.y = f2fp8x4(v1.x, v1.y, v1.z, v1.w);
      o.z = f2fp8x4(v2.x, v2.y, v2.z, v2.w);
      o.w = f2fp8x4(v3.x, v3.y, v3.z, v3.w);
    } else {
      o = uint4{0, 0, 0, 0};
    }
    *(uint4*)&x8[idx16] = o;
  } else {
    int wb = b - XB_BLOCKS;
    if (wb < 32) {
      // W1 [512x256] -> W1T8 [256x512] fp8, 16/thread
      int idx16 = (wb * 256 + threadIdx.x) * 16;
      int n = idx16 >> 9;
      float f[16];
#pragma unroll
      for (int j = 0; j < 16; j++) f[j] = W1[(size_t)((idx16 & 511) + j) * 256 + n];
      uint4 o;
      o.x = f2fp8x4(f[0], f[1], f[2], f[3]);
      o.y = f2fp8x4(f[4], f[5], f[6], f[7]);
      o.z = f2fp8x4(f[8], f[9], f[10], f[11]);
      o.w = f2fp8x4(f[12], f[13], f[14], f[15]);
      *(uint4*)&W1T8[idx16] = o;
    } else if (wb < 48) {
      // W2 [256x256] -> W2T8 [256x256] fp8
      int idx16 = ((wb - 32) * 256 + threadIdx.x) * 16;
      int n = idx16 >> 8;
      float f[16];
#pragma unroll
      for (int j = 0; j < 16; j++) f[j] = W2[(size_t)((idx16 & 255) + j) * 256 + n];
      uint4 o;
      o.x = f2fp8x4(f[0], f[1], f[2], f[3]);
      o.y = f2fp8x4(f[4], f[5], f[6], f[7]);
      o.z = f2fp8x4(f[8], f[9], f[10], f[11]);
      o.w = f2fp8x4(f[12], f[13], f[14], f[15]);
      *(uint4*)&W2T8[idx16] = o;
    } else {
      // W3 [256x64] -> W3T8 [64x256] fp8
      int idx16 = ((wb - 48) * 256 + threadIdx.x) * 16;
      int n = idx16 >> 8;
      float f[16];
#pragma unroll
      for (int j = 0; j < 16; j++) f[j] = W3[(size_t)((idx16 & 255) + j) * 64 + n];
      uint4 o;
      o.x = f2fp8x4(f[0], f[1], f[2], f[3]);
      o.y = f2fp8x4(f[4], f[5], f[6], f[7]);
      o.z = f2fp8x4(f[8], f[9], f[10], f[11]);
      o.w = f2fp8x4(f[12], f[13], f[14], f[15]);
      *(uint4*)&W3T8[idx16] = o;
    }
  }
}

// ---------- scan ----------
__global__ __launch_bounds__(256) void gcn_scan_blocks_k(
    const int* __restrict__ cnt, int* __restrict__ blockSum, int nNodes) {
  __shared__ int sw[4];
  int t = threadIdx.x;
  int i = blockIdx.x * 256 + t;
  int v = (i < nNodes) ? cnt[i] : 0;
  for (int off = 32; off > 0; off >>= 1) v += __shfl_down(v, off);
  if ((t & 63) == 0) sw[t >> 6] = v;
  __syncthreads();
  if (t == 0) blockSum[blockIdx.x] = sw[0] + sw[1] + sw[2] + sw[3];
}

__global__ __launch_bounds__(256) void gcn_scan_tops_k(
    int* __restrict__ blockSum, int nBlocks) {
  __shared__ int sb[256];
  int t = threadIdx.x;
  int v = (t < nBlocks) ? blockSum[t] : 0;
  sb[t] = v;
  __syncthreads();
  for (int off = 1; off < 256; off <<= 1) {
    int x = (t >= off) ? sb[t - off] : 0;
    __syncthreads();
    sb[t] += x;
    __syncthreads();
  }
  if (t < nBlocks) blockSum[t] = sb[t] - v;  // exclusive
}

__global__ __launch_bounds__(256) void gcn_scan_final_k(
    const int* __restrict__ cnt, const int* __restrict__ blockSum,
    int* __restrict__ rs, int* __restrict__ cur, float* __restrict__ dinv,
    int nNodes, int E) {
  __shared__ int sb[256];
  int t = threadIdx.x;
  int i = blockIdx.x * 256 + t;
  int v = (i < nNodes) ? cnt[i] : 0;
  sb[t] = v;
  __syncthreads();
  for (int off = 1; off < 256; off <<= 1) {
    int x = (t >= off) ? sb[t - off] : 0;
    __syncthreads();
    sb[t] += x;
    __syncthreads();
  }
  if (i < nNodes) {
    int off = blockSum[blockIdx.x] + sb[t] - v;
    rs[i] = off; cur[i] = off;
    dinv[i] = rsqrtf(1.0f + (float)v);
  }
  if (i == 0) rs[nNodes] = E;
}

// scatter edges sorted by dst; pack (src, norm) into one int2
__global__ void gcn_scatter_k(const int* __restrict__ src, const int* __restrict__ dst,
                              int* __restrict__ cur, const float* __restrict__ dinv,
                              int2* __restrict__ e2, int E) {
  int e = blockIdx.x * 256 + threadIdx.x;
  if (e < E) {
    int d = dst[e];
    int s = src[e];
    int p = atomicAdd(&cur[d], 1);
    int2 v; v.x = s; v.y = __float_as_int(dinv[s] * dinv[d]);
    e2[p] = v;
  }
}

// ---------- fp8 x fp8 MFMA GEMM, fp8 out: C8 = fp8(A8 @ Bt8^T), 128 x BN tile ----------
template<int BN, int WTN>
__global__ __launch_bounds__(256) void gcn_gemm_f8_k(
    const unsigned char* __restrict__ A8,   // [MPAD x K] fp8
    const unsigned char* __restrict__ Bt8,  // [N x K]    fp8
    unsigned char* __restrict__ C8,         // [MPAD x N] fp8
    int K, int N) {
  __shared__ __align__(16) unsigned char lds_a[128 * 32];
  __shared__ __align__(16) unsigned char lds_b[BN * 32];
  const int t = threadIdx.x;
  const int wave = t >> 6, lane = t & 63;
  const int wr = wave >> 1, wc = wave & 1;
  const int quad = lane >> 4, lrow = lane & 15;
  const int m0 = blockIdx.x * 128;
  const int n0 = blockIdx.y * BN;

  f32x4 acc[4][WTN] = {};

  for (int k0 = 0; k0 < K; k0 += 32) {
    __syncthreads();
    {
      int r = t >> 1, c = (t & 1) * 16;
      async_copy16(&A8[(size_t)(m0 + r) * K + k0 + c], &lds_a[t * 16]);
    }
    for (int q = t; q < BN * 2; q += 256) {
      int r = q >> 1, c = (q & 1) * 16;
      async_copy16(&Bt8[(size_t)(n0 + r) * K + k0 + c], &lds_b[q * 16]);
    }
    __syncthreads();
    long af[4], bfr[WTN];
#pragma unroll
    for (int mt = 0; mt < 4; mt++)
      af[mt] = *(const long*)&lds_a[(wr * 64 + mt * 16 + lrow) * 32 + quad * 8];
#pragma unroll
    for (int nt = 0; nt < WTN; nt++)
      bfr[nt] = *(const long*)&lds_b[(wc * (BN / 2) + nt * 16 + lrow) * 32 + quad * 8];
#pragma unroll
    for (int mt = 0; mt < 4; mt++)
#pragma unroll
      for (int nt = 0; nt < WTN; nt++)
        acc[mt][nt] = __builtin_amdgcn_mfma_f32_16x16x32_fp8_fp8(af[mt], bfr[nt], acc[mt][nt], 0, 0, 0);
  }

#pragma unroll
  for (int mt = 0; mt < 4; mt++)
#pragma unroll
    for (int nt = 0; nt < WTN; nt++)
#pragma unroll
      for (int r = 0; r < 4; r++) {
        int row = m0 + wr * 64 + mt * 16 + quad * 4 + r;
        int col = n0 + wc * (BN / 2) + nt * 16 + lrow;
        C8[(size_t)row * N + col] = f2fp8(acc[mt][nt][r]);
      }
}

// ---------- aggregation over fp8 rows, fused bias+self+ReLU, fp8 out ----------
// 2 edges per wave (32 lanes x 8B fp8 per row), unroll x4 -> 8 edges in flight.
template<int D>  // D = 256
__global__ __launch_bounds__(256) void gcn_agg_relu_k(
    const unsigned char* __restrict__ h8, const int* __restrict__ rs,
    const int2* __restrict__ e2, const float* __restrict__ dinv,
    const float* __restrict__ bias, unsigned char* __restrict__ out8, int nNodes) {
  int wave = threadIdx.x >> 6, lane = threadIdx.x & 63;
  int i = blockIdx.x * 4 + wave;
  if (i >= nNodes) return;
  int half = lane >> 5, sub = lane & 31;
  int f0 = sub * 8;
  float di = dinv[i];
  uint2 dsel = *(const uint2*)&h8[(size_t)i * D + f0];
  float sv[8];
  fp8x8_to_f32(dsel, sv);
  float wself = (half == 0) ? di * di : 0.0f;
  float acc[8];
#pragma unroll
  for (int j = 0; j < 8; j++) acc[j] = sv[j] * wself;

  int e0 = rs[i], e1 = rs[i + 1];
  int nIter = (e1 - e0 + 7) >> 3;
  int e = e0 + half;
  for (int k = 0; k < nIter; k++) {
    int idx[4]; float w[4];
#pragma unroll
    for (int u = 0; u < 4; u++) {
      int ee = e + 2 * u;
      bool v = ee < e1;
      int2 pr = e2[v ? ee : e0];
      idx[u] = v ? pr.x : i;
      w[u] = v ? __int_as_float(pr.y) : 0.0f;
    }
    uint2 d0 = *(const uint2*)&h8[(size_t)idx[0] * D + f0];
    uint2 d1 = *(const uint2*)&h8[(size_t)idx[1] * D + f0];
    uint2 d2 = *(const uint2*)&h8[(size_t)idx[2] * D + f0];
    uint2 d3 = *(const uint2*)&h8[(size_t)idx[3] * D + f0];
    float r0[8], r1[8], r2[8], r3[8];
    fp8x8_to_f32(d0, r0); fp8x8_to_f32(d1, r1);
    fp8x8_to_f32(d2, r2); fp8x8_to_f32(d3, r3);
#pragma unroll
    for (int j = 0; j < 8; j++)
      acc[j] += r0[j] * w[0] + r1[j] * w[1] + r2[j] * w[2] + r3[j] * w[3];
    e += 8;
  }
#pragma unroll
  for (int j = 0; j < 8; j++) acc[j] += __shfl_xor(acc[j], 32);
  if (half == 0) {
    float r[8];
#pragma unroll
    for (int j = 0; j < 8; j++) {
      float z = acc[j] + bias[f0 + j];
      r[j] = z > 0.0f ? z : 0.0f;
    }
    uint2 o;
    o.x = f2fp8x4(r[0], r[1], r[2], r[3]);
    o.y = f2fp8x4(r[4], r[5], r[6], r[7]);
    *(uint2*)&out8[(size_t)i * D + f0] = o;
  }
}

// final layer: D=64 fp8 rows; 4 edges per wave (16 lanes x 4B), softmax+log_softmax
__global__ __launch_bounds__(256) void gcn_agg_final_k(
    const unsigned char* __restrict__ h8, const int* __restrict__ rs,
    const int2* __restrict__ e2, const float* __restrict__ dinv,
    const float* __restrict__ bias, float* __restrict__ out, int nNodes) {
  int wave = threadIdx.x >> 6, lane = threadIdx.x & 63;
  int i = blockIdx.x * 4 + wave;
  if (i >= nNodes) return;
  int qtr = lane >> 4, sub = lane & 15;
  int f0 = sub * 4;
  float di = dinv[i];
  unsigned int dself = *(const unsigned int*)&h8[(size_t)i * 64 + f0];
  float sv[4];
  fp8x4_to_f32(dself, sv);
  float wself = (qtr == 0) ? di * di : 0.0f;
  float acc[4];
#pragma unroll
  for (int j = 0; j < 4; j++) acc[j] = sv[j] * wself;

  int e0 = rs[i], e1 = rs[i + 1];
  int nIter = (e1 - e0 + 7) >> 3;
  int e = e0 + qtr;
  for (int k = 0; k < nIter; k++) {
    int idx[2]; float w[2];
#pragma unroll
    for (int u = 0; u < 2; u++) {
      int ee = e + 4 * u;
      bool v = ee < e1;
      int2 pr = e2[v ? ee : e0];
      idx[u] = v ? pr.x : i;
      w[u] = v ? __int_as_float(pr.y) : 0.0f;
    }
    unsigned int d0 = *(const unsigned int*)&h8[(size_t)idx[0] * 64 + f0];
    unsigned int d1 = *(const unsigned int*)&h8[(size_t)idx[1] * 64 + f0];
    float r0[4], r1[4];
    fp8x4_to_f32(d0, r0); fp8x4_to_f32(d1, r1);
#pragma unroll
    for (int j = 0; j < 4; j++)
      acc[j] += r0[j] * w[0] + r1[j] * w[1];
    e += 8;
  }
#pragma unroll
  for (int j = 0; j < 4; j++) {
    acc[j] += __shfl_xor(acc[j], 16);
    acc[j] += __shfl_xor(acc[j], 32);
    acc[j] += bias[f0 + j];
  }
  // softmax over 64 features (16 lanes x 4 regs; all lanes hold full sums)
  float m = fmaxf(fmaxf(acc[0], acc[1]), fmaxf(acc[2], acc[3]));
#pragma unroll
  for (int off = 8; off > 0; off >>= 1) m = fmaxf(m, __shfl_xor(m, off));
  float ex[4], s = 0.0f;
#pragma unroll
  for (int j = 0; j < 4; j++) { ex[j] = __expf(acc[j] - m); s += ex[j]; }
#pragma unroll
  for (int off = 8; off > 0; off >>= 1) s += __shfl_xor(s, off);
  float rcs = 1.0f / s;
  float p[4], s2 = 0.0f;
#pragma unroll
  for (int j = 0; j < 4; j++) { p[j] = ex[j] * rcs; s2 += __expf(p[j]); }
#pragma unroll
  for (int off = 8; off > 0; off >>= 1) s2 += __shfl_xor(s2, off);
  float ls = __logf(s2);
  if (qtr == 0) {
    float4 o; o.x = p[0] - ls; o.y = p[1] - ls; o.z = p[2] - ls; o.w = p[3] - ls;
    *(float4*)&out[(size_t)i * 64 + f0] = o;
  }
}

// ---------- launch ----------
extern "C" void kernel_launch(void* const* d_in, const int* in_sizes, int n_in,
                              void* d_out, int out_size, void* d_ws, size_t ws_size,
                              hipStream_t stream) {
  const float* x    = (const float*)d_in[0];
  const int*   eidx = (const int*)d_in[1];
  const float* W1   = (const float*)d_in[2];
  const float* b1   = (const float*)d_in[3];
  const float* W2   = (const float*)d_in[4];
  const float* b2   = (const float*)d_in[5];
  const float* W3   = (const float*)d_in[6];
  const float* b3   = (const float*)d_in[7];
  float* out = (float*)d_out;

  const int E = in_sizes[1] / 2;            // 800000
  const int* src = eidx;
  const int* dst = eidx + E;

  char* p = (char*)d_ws;
  auto alloc = [&](size_t bytes) -> void* {
    void* r = (void*)p;
    p += (bytes + 255) & ~(size_t)255;
    return r;
  };
  unsigned char*  x8   = (unsigned char*)alloc((size_t)MPAD * 512);
  unsigned char*  g8   = (unsigned char*)alloc((size_t)MPAD * 256);  // gemm out fp8
  unsigned char*  a8   = (unsigned char*)alloc((size_t)MPAD * 256);  // agg out fp8
  unsigned char*  g83  = (unsigned char*)alloc((size_t)MPAD * 64);
  unsigned char*  W1T8 = (unsigned char*)alloc((size_t)256 * 512);
  unsigned char*  W2T8 = (unsigned char*)alloc((size_t)256 * 256);
  unsigned char*  W3T8 = (unsigned char*)alloc((size_t)64 * 256);
  int*   cnt  = (int*)alloc((size_t)NN * 4);
  int*   rs   = (int*)alloc((size_t)(NN + 1) * 4);
  int*   cur  = (int*)alloc((size_t)NN * 4);
  float* dinv = (float*)alloc((size_t)NN * 4);
  int2*  e2   = (int2*)alloc((size_t)E * 8);
  int*   bsum = (int*)alloc((size_t)SCAN_BLOCKS * 4);

  const int EB = (E + 255) / 256;
  gcn_zero_k<<<SCAN_BLOCKS, 256, 0, stream>>>(cnt, NN);
  gcn_count_k<<<EB, 256, 0, stream>>>(dst, cnt, E);
  gcn_prep_k<<<XB_BLOCKS + WB_BLOCKS, 256, 0, stream>>>(
      x, x8, W1, W2, W3, W1T8, W2T8, W3T8);
  gcn_scan_blocks_k<<<SCAN_BLOCKS, 256, 0, stream>>>(cnt, bsum, NN);
  gcn_scan_tops_k<<<1, 256, 0, stream>>>(bsum, SCAN_BLOCKS);
  gcn_scan_final_k<<<SCAN_BLOCKS, 256, 0, stream>>>(cnt, bsum, rs, cur, dinv, NN, E);
  gcn_scatter_k<<<EB, 256, 0, stream>>>(src, dst, cur, dinv, e2, E);

  const int MB = MPAD / 128;  // 391
  // layer 1 (fp8)
  gcn_gemm_f8_k<128, 4><<<dim3(MB, 2), 256, 0, stream>>>(x8, W1T8, g8, 512, 256);
  gcn_agg_relu_k<256><<<(NN + 3) / 4, 256, 0, stream>>>(g8, rs, e2, dinv, b1, a8, NN);
  // layer 2 (fp8)
  gcn_gemm_f8_k<128, 4><<<dim3(MB, 2), 256, 0, stream>>>(a8, W2T8, g8, 256, 256);
  gcn_agg_relu_k<256><<<(NN + 3) / 4, 256, 0, stream>>>(g8, rs, e2, dinv, b2, a8, NN);
  // layer 3 (fp8) + fused softmax/log_softmax
  gcn_gemm_f8_k<64, 2><<<dim3(MB, 1), 256, 0, stream>>>(a8, W3T8, g83, 256, 64);
  gcn_agg_final_k<<<(NN + 3) / 4, 256, 0, stream>>>(g83, rs, e2, dinv, b3, out, NN);

  (void)n_in; (void)out_size; (void)ws_size;
}